// Round 4
// baseline (884.337 us; speedup 1.0000x reference)
//
#include <hip/hip_runtime.h>
#include <hip/hip_bf16.h>

#define NN 50000
#define NE 800000
#define DIN 128
#define HC 256
#define NHEAD 4
#define CDIM 64
#define NGRAPH 512
#define NCLS 10
#define NEG_SLOPE 0.2f
#define NB 196  // ceil(NN/256)

typedef __hip_bfloat16 bf16;

__device__ __forceinline__ float bf2f(unsigned short u) {
  union { unsigned int i; float f; } x;
  x.i = ((unsigned int)u) << 16;
  return x.f;
}
__device__ __forceinline__ unsigned short f2bf(float f) {
  bf16 v = __float2bfloat16(f);
  union { bf16 b; unsigned short s; } x;
  x.b = v;
  return x.s;
}
__device__ __forceinline__ float lrelu(float x) { return x >= 0.f ? x : NEG_SLOPE * x; }
// NaN-propagating relu (fmaxf would silently clamp NaN to 0)
__device__ __forceinline__ float relu(float x) { return x < 0.f ? 0.f : x; }

// ---------------- zero scratch accumulators ----------------
__global__ void zero_kernel(int* __restrict__ p, int n) {
  int i = blockIdx.x * 256 + threadIdx.x;
  if (i < n) p[i] = 0;
}

// ---------------- GEMM1 + fused attention logits (layer 1) ----------------
// h1[row, 0..255] = x[row, :] @ W1   (fp32 accumulate, bf16 store)
// als1[row,h] = sum_c h1[row,h*64+c]*a_src[h,c]  (wave w == head w)
__global__ __launch_bounds__(256) void gemm1_kernel(const float* __restrict__ x,
                                                    const float* __restrict__ W1,
                                                    const float* __restrict__ a_src,
                                                    const float* __restrict__ a_dst,
                                                    unsigned short* __restrict__ h1,
                                                    float* __restrict__ als,
                                                    float* __restrict__ ald) {
  __shared__ float xs[DIN];
  int row = blockIdx.x;
  int t = threadIdx.x;
  if (t < DIN) xs[t] = x[row * DIN + t];
  __syncthreads();
  float acc = 0.f;
  for (int k = 0; k < DIN; k++) {
    acc += xs[k] * W1[k * HC + t];
  }
  h1[row * HC + t] = f2bf(acc);
  // fused attention logits: wave w holds cols 64w..64w+63 == head w
  float ps = acc * a_src[t];
  float pd = acc * a_dst[t];
  for (int o = 1; o < 64; o <<= 1) {
    ps += __shfl_xor(ps, o, 64);
    pd += __shfl_xor(pd, o, 64);
  }
  int lane = t & 63;
  int wave = t >> 6;
  if (lane == 0) {
    als[row * NHEAD + wave] = ps;
    ald[row * NHEAD + wave] = pd;
  }
}

// ---------------- edge histogram (deg by dst) + graph counts ----------------
__global__ void hist_kernel(const int* __restrict__ ei, const int* __restrict__ batch,
                            int* __restrict__ deg, int* __restrict__ counts) {
  int i = blockIdx.x * 256 + threadIdx.x;
  if (i < NE) atomicAdd(&deg[ei[NE + i]], 1);
  if (i < NN) atomicAdd(&counts[batch[i]], 1);
}

// ---------------- exclusive scan of deg -> off, cursor ----------------
__global__ void scan_a(const int* __restrict__ deg, int* __restrict__ bsum) {
  __shared__ int sm[256];
  int t = threadIdx.x, i = blockIdx.x * 256 + t;
  sm[t] = (i < NN) ? deg[i] : 0;
  __syncthreads();
  for (int s = 128; s > 0; s >>= 1) {
    if (t < s) sm[t] += sm[t + s];
    __syncthreads();
  }
  if (t == 0) bsum[blockIdx.x] = sm[0];
}
__global__ void scan_b(const int* __restrict__ bsum, int* __restrict__ bscan) {
  __shared__ int sm[256];
  int t = threadIdx.x;
  int own = (t < NB) ? bsum[t] : 0;
  sm[t] = own;
  __syncthreads();
  for (int s = 1; s < 256; s <<= 1) {
    int v = (t >= s) ? sm[t - s] : 0;
    __syncthreads();
    sm[t] += v;
    __syncthreads();
  }
  if (t < NB) bscan[t] = sm[t] - own;  // exclusive over block sums
}
__global__ void scan_c(const int* __restrict__ deg, const int* __restrict__ bscan,
                       int* __restrict__ off, int* __restrict__ cursor) {
  __shared__ int sm[256];
  int t = threadIdx.x, i = blockIdx.x * 256 + t;
  int d = (i < NN) ? deg[i] : 0;
  sm[t] = d;
  __syncthreads();
  for (int s = 1; s < 256; s <<= 1) {
    int v = (t >= s) ? sm[t - s] : 0;
    __syncthreads();
    sm[t] += v;
    __syncthreads();
  }
  int excl = bscan[blockIdx.x] + sm[t] - d;
  if (i < NN) {
    off[i] = excl;
    cursor[i] = excl;
    if (i == NN - 1) off[NN] = excl + d;
  }
}

// ---------------- scatter edges into CSR buckets ----------------
__global__ void scatter_kernel(const int* __restrict__ ei, int* __restrict__ cursor,
                               int* __restrict__ esrc) {
  int e = blockIdx.x * 256 + threadIdx.x;
  if (e >= NE) return;
  int d = ei[NE + e];
  int p = atomicAdd(&cursor[d], 1);
  esrc[p] = ei[e];
}

// ---------------- GAT layer1 aggregation: online softmax, wave per (node,head) -------
__global__ __launch_bounds__(256) void agg1_kernel(const unsigned short* __restrict__ h1,
                                                   const float* __restrict__ als,
                                                   const float* __restrict__ ald,
                                                   const int* __restrict__ off,
                                                   const int* __restrict__ esrc,
                                                   const float* __restrict__ b1,
                                                   unsigned short* __restrict__ out1) {
  int node = blockIdx.x;
  int hh = threadIdx.x >> 6, lane = threadIdx.x & 63;
  int ch = hh * CDIM + lane;
  float ad = ald[node * NHEAD + hh];
  // self-loop initializes online-softmax state
  float e0 = lrelu(als[node * NHEAD + hh] + ad);
  float mm = e0, zz = 1.f;
  float acc = bf2f(h1[node * HC + ch]);
  int beg = off[node], end = off[node + 1];
  for (int k = beg; k < end; k++) {
    int s = esrc[k];
    float e = lrelu(als[s * NHEAD + hh] + ad);
    float hv = bf2f(h1[s * HC + ch]);
    float nm = fmaxf(mm, e);
    float sf = expf(mm - nm), sg = expf(e - nm);
    zz = zz * sf + sg;
    acc = acc * sf + sg * hv;
    mm = nm;
  }
  float v = acc / zz + b1[ch];
  out1[node * HC + ch] = f2bf(v);
}

// ---------------- BN stats over out1 ----------------
__global__ __launch_bounds__(256) void bnstats_kernel(const unsigned short* __restrict__ out1,
                                                      float* __restrict__ bnsum,
                                                      float* __restrict__ bnsumsq) {
  int t = threadIdx.x;
  float s = 0.f, s2 = 0.f;
  for (int r = blockIdx.x; r < NN; r += gridDim.x) {
    float v = bf2f(out1[r * HC + t]);
    s += v;
    s2 += v * v;
  }
  atomicAdd(&bnsum[t], s);
  atomicAdd(&bnsumsq[t], s2);
}
__global__ void bnfin_kernel(const float* __restrict__ bnsum, const float* __restrict__ bnsumsq,
                             const float* __restrict__ gamma,
                             const float* __restrict__ beta,
                             float* __restrict__ scale, float* __restrict__ shift) {
  int t = threadIdx.x;
  float mu = bnsum[t] / (float)NN;
  float var = bnsumsq[t] / (float)NN - mu * mu;
  float sc = gamma[t] * rsqrtf(var + 1e-5f);
  scale[t] = sc;
  shift[t] = beta[t] - mu * sc;
}

// ---------------- GEMM2 (BN+ReLU fused on A) + fused attention logits (layer 2) -----
// 4 rows per block; thread (r=t>>6, col=t&63). Wave w == row w -> als2 reduction.
__global__ __launch_bounds__(256) void gemm2_kernel(const unsigned short* __restrict__ out1,
                                                    const float* __restrict__ W2,
                                                    const float* __restrict__ scale,
                                                    const float* __restrict__ shift,
                                                    const float* __restrict__ a_src2,
                                                    const float* __restrict__ a_dst2,
                                                    unsigned short* __restrict__ h2,
                                                    float* __restrict__ als2,
                                                    float* __restrict__ ald2) {
  __shared__ float as[4][HC];
  int t = threadIdx.x;
  int r0 = blockIdx.x * 4;
  int r = t >> 6, col = t & 63;
  // stage BN+ReLU activations for 4 rows: thread t loads 4 consecutive cols
  int c0 = (t & 63) * 4;
  int lr = t >> 6;
  for (int j = 0; j < 4; j++) {
    float v = bf2f(out1[(r0 + lr) * HC + c0 + j]);
    as[lr][c0 + j] = relu(v * scale[c0 + j] + shift[c0 + j]);
  }
  __syncthreads();
  float acc = 0.f;
  for (int k = 0; k < HC; k++) {
    acc += as[r][k] * W2[k * CDIM + col];
  }
  int row = r0 + r;
  h2[row * CDIM + col] = f2bf(acc);
  float ps = acc * a_src2[col];
  float pd = acc * a_dst2[col];
  for (int o = 1; o < 64; o <<= 1) {
    ps += __shfl_xor(ps, o, 64);
    pd += __shfl_xor(pd, o, 64);
  }
  if (col == 0) {
    als2[row] = ps;
    ald2[row] = pd;
  }
}

// ---------------- GAT layer2 aggregation + ReLU + graph pooling (sum) ----------------
__global__ __launch_bounds__(256) void agg2_kernel(const unsigned short* __restrict__ h2,
                                                   const float* __restrict__ als2,
                                                   const float* __restrict__ ald2,
                                                   const int* __restrict__ off,
                                                   const int* __restrict__ esrc,
                                                   const float* __restrict__ b2,
                                                   const int* __restrict__ batch,
                                                   float* __restrict__ pooled) {
  int node = blockIdx.x * 4 + (threadIdx.x >> 6);
  int lane = threadIdx.x & 63;
  float ad = ald2[node];
  float e0 = lrelu(als2[node] + ad);
  float mm = e0, zz = 1.f;
  float acc = bf2f(h2[node * CDIM + lane]);
  int beg = off[node], end = off[node + 1];
  for (int k = beg; k < end; k++) {
    int s = esrc[k];
    float e = lrelu(als2[s] + ad);
    float hv = bf2f(h2[s * CDIM + lane]);
    float nm = fmaxf(mm, e);
    float sf = expf(mm - nm), sg = expf(e - nm);
    zz = zz * sf + sg;
    acc = acc * sf + sg * hv;
    mm = nm;
  }
  float v = relu(acc / zz + b2[lane]);
  atomicAdd(&pooled[batch[node] * CDIM + lane], v);
}

// ---------------- pooled mean + classifier (f32 output) ----------------
__global__ void cls_kernel(const float* __restrict__ pooled, const int* __restrict__ counts,
                           const float* __restrict__ cW1,
                           const float* __restrict__ cb1,
                           const float* __restrict__ cW2,
                           const float* __restrict__ cb2,
                           float* __restrict__ out) {
  __shared__ float p[64];
  __shared__ float z[32];
  int g = blockIdx.x, t = threadIdx.x;
  int c = counts[g];
  float cnt = (float)(c > 0 ? c : 1);
  p[t] = pooled[g * CDIM + t] / cnt;
  __syncthreads();
  if (t < 32) {
    float a = cb1[t];
    for (int k = 0; k < 64; k++) a += p[k] * cW1[k * 32 + t];
    z[t] = relu(a);
  }
  __syncthreads();
  if (t < NCLS) {
    float a = cb2[t];
    for (int k = 0; k < 32; k++) a += z[k] * cW2[k * NCLS + t];
    out[g * NCLS + t] = a;
  }
}

extern "C" void kernel_launch(void* const* d_in, const int* in_sizes, int n_in,
                              void* d_out, int out_size, void* d_ws, size_t ws_size,
                              hipStream_t stream) {
  const float* x = (const float*)d_in[0];
  const int* edge_index = (const int*)d_in[1];
  const int* batch = (const int*)d_in[2];
  const float* W1 = (const float*)d_in[3];
  const float* a_src1 = (const float*)d_in[4];
  const float* a_dst1 = (const float*)d_in[5];
  const float* b1 = (const float*)d_in[6];
  const float* gamma = (const float*)d_in[7];
  const float* beta = (const float*)d_in[8];
  const float* W2 = (const float*)d_in[9];
  const float* a_src2 = (const float*)d_in[10];
  const float* a_dst2 = (const float*)d_in[11];
  const float* b2 = (const float*)d_in[12];
  const float* cW1 = (const float*)d_in[13];
  const float* cb1 = (const float*)d_in[14];
  const float* cW2 = (const float*)d_in[15];
  const float* cb2 = (const float*)d_in[16];

  // ---- workspace layout ----
  // zero region (contiguous, zeroed every call): deg | bnsum | bnsumsq | pooled | counts
  int* deg = (int*)d_ws;
  float* bnsum = (float*)(deg + NN);
  float* bnsumsq = bnsum + HC;
  float* pooled = bnsumsq + HC;
  int* counts = (int*)(pooled + NGRAPH * CDIM);
  const int ZWORDS = NN + HC + HC + NGRAPH * CDIM + NGRAPH;
  char* p = (char*)(counts + NGRAPH);
  auto align256 = [&](char*& q) {
    size_t a = (size_t)(q - (char*)d_ws);
    a = (a + 255) & ~(size_t)255;
    q = (char*)d_ws + a;
  };
  align256(p);
  int* offs = (int*)p;            p += (size_t)(NN + 1) * 4; align256(p);
  int* cursor = (int*)p;          p += (size_t)NN * 4;       align256(p);
  int* esrc = (int*)p;            p += (size_t)NE * 4;       align256(p);
  int* bsum = (int*)p;            p += 256 * 4;              align256(p);
  int* bscan = (int*)p;           p += 256 * 4;              align256(p);
  unsigned short* h1 = (unsigned short*)p;   p += (size_t)NN * HC * 2;   align256(p);
  unsigned short* out1 = (unsigned short*)p; p += (size_t)NN * HC * 2;   align256(p);
  unsigned short* h2 = (unsigned short*)p;   p += (size_t)NN * CDIM * 2; align256(p);
  float* als1 = (float*)p;        p += (size_t)NN * NHEAD * 4; align256(p);
  float* ald1 = (float*)p;        p += (size_t)NN * NHEAD * 4; align256(p);
  float* als2v = (float*)p;       p += (size_t)NN * 4;         align256(p);
  float* ald2v = (float*)p;       p += (size_t)NN * 4;         align256(p);
  float* bnscale = (float*)p;     p += HC * 4;                 align256(p);
  float* bnshift = (float*)p;     p += HC * 4;                 align256(p);

  zero_kernel<<<(ZWORDS + 255) / 256, 256, 0, stream>>>((int*)d_ws, ZWORDS);
  gemm1_kernel<<<NN, 256, 0, stream>>>(x, W1, a_src1, a_dst1, h1, als1, ald1);
  hist_kernel<<<(NE + 255) / 256, 256, 0, stream>>>(edge_index, batch, deg, counts);
  scan_a<<<NB, 256, 0, stream>>>(deg, bsum);
  scan_b<<<1, 256, 0, stream>>>(bsum, bscan);
  scan_c<<<NB, 256, 0, stream>>>(deg, bscan, offs, cursor);
  scatter_kernel<<<(NE + 255) / 256, 256, 0, stream>>>(edge_index, cursor, esrc);
  agg1_kernel<<<NN, 256, 0, stream>>>(h1, als1, ald1, offs, esrc, b1, out1);
  bnstats_kernel<<<256, 256, 0, stream>>>(out1, bnsum, bnsumsq);
  bnfin_kernel<<<1, 256, 0, stream>>>(bnsum, bnsumsq, gamma, beta, bnscale, bnshift);
  gemm2_kernel<<<NN / 4, 256, 0, stream>>>(out1, W2, bnscale, bnshift, a_src2, a_dst2,
                                           h2, als2v, ald2v);
  agg2_kernel<<<NN / 4, 256, 0, stream>>>(h2, als2v, ald2v, offs, esrc, b2, batch, pooled);
  cls_kernel<<<NGRAPH, 64, 0, stream>>>(pooled, counts, cW1, cb1, cW2, cb2,
                                        (float*)d_out);
}

// Round 6
// 499.776 us; speedup vs baseline: 1.7695x; 1.7695x over previous
//
#include <hip/hip_runtime.h>
#include <hip/hip_bf16.h>

#define NN 50000
#define NE 800000
#define DIN 128
#define HC 256
#define NHEAD 4
#define CDIM 64
#define NGRAPH 512
#define NCLS 10
#define NEG_SLOPE 0.2f
#define NB 196   // ceil(NN/256)
#define NT1 3125 // NN/16 M-tiles

typedef __hip_bfloat16 bf16;
typedef __attribute__((ext_vector_type(8))) short short8;
typedef __attribute__((ext_vector_type(4))) float f32x4;

__device__ __forceinline__ float bf2f(unsigned short u) {
  union { unsigned int i; float f; } x;
  x.i = ((unsigned int)u) << 16;
  return x.f;
}
__device__ __forceinline__ unsigned short f2bf(float f) {
  bf16 v = __float2bfloat16(f);
  union { bf16 b; unsigned short s; } x;
  x.b = v;
  return x.s;
}
__device__ __forceinline__ float lrelu(float x) { return x >= 0.f ? x : NEG_SLOPE * x; }
// NaN-propagating relu (fmaxf would silently clamp NaN to 0)
__device__ __forceinline__ float relu(float x) { return x < 0.f ? 0.f : x; }

// ---------------- zero scratch accumulators ----------------
__global__ void zero_kernel(int* __restrict__ p, int n) {
  int i = blockIdx.x * 256 + threadIdx.x;
  if (i < n) p[i] = 0;
}

// ---------------- x f32 -> bf16 ----------------
__global__ void cvt_x_kernel(const float* __restrict__ x, unsigned short* __restrict__ xb) {
  int i = blockIdx.x * 256 + threadIdx.x;  // i < NN*DIN/4
  const float4 v = ((const float4*)x)[i];
  ushort4 o;
  o.x = f2bf(v.x); o.y = f2bf(v.y); o.z = f2bf(v.z); o.w = f2bf(v.w);
  ((ushort4*)xb)[i] = o;
}

// ---------------- repack W1,W2 (f32) into MFMA B-frag bf16 order ----------------
// B frag for 16x16x32: lane holds col n = lane&15, k = (lane>>4)*8 + j, j=0..7
__global__ void repack_kernel(const float* __restrict__ W1, const float* __restrict__ W2,
                              unsigned short* __restrict__ W1p, unsigned short* __restrict__ W2p) {
  int i = blockIdx.x * 256 + threadIdx.x;
  if (i < 16 * 4 * 64 * 8) {  // W1: [128,256] -> ng(16) kk(4) lane(64) j(8)
    int j = i & 7, lane = (i >> 3) & 63, kk = (i >> 9) & 3, ng = i >> 11;
    int n = ng * 16 + (lane & 15);
    int k = kk * 32 + (lane >> 4) * 8 + j;
    W1p[i] = f2bf(W1[k * HC + n]);
  }
  int i2 = i - 16 * 4 * 64 * 8;
  if (i2 >= 0 && i2 < 4 * 8 * 64 * 8) {  // W2: [256,64] -> ng(4) kk(8) lane(64) j(8)
    int j = i2 & 7, lane = (i2 >> 3) & 63, kk = (i2 >> 9) & 7, ng = i2 >> 12;
    int n = ng * 16 + (lane & 15);
    int k = kk * 32 + (lane >> 4) * 8 + j;
    W2p[i2] = f2bf(W2[k * CDIM + n]);
  }
}

// ---------------- GEMM1: h1[NN,256] = xb[NN,128] @ W1  (bf16 MFMA) ----------------
__global__ __launch_bounds__(256) void gemm1_kernel(const unsigned short* __restrict__ xb,
                                                    const unsigned short* __restrict__ W1p,
                                                    unsigned short* __restrict__ h1) {
  int wave = threadIdx.x >> 6, lane = threadIdx.x & 63;
  int tile = blockIdx.x * 4 + wave;
  if (tile >= NT1) return;
  int r0 = tile * 16, m = lane & 15, quad = lane >> 4;
  int row = r0 + m;
  short8 a[4];
#pragma unroll
  for (int kk = 0; kk < 4; kk++)
    a[kk] = *(const short8*)(xb + row * DIN + kk * 32 + quad * 8);
#pragma unroll
  for (int ng = 0; ng < 16; ng++) {
    f32x4 acc = {0.f, 0.f, 0.f, 0.f};
#pragma unroll
    for (int kk = 0; kk < 4; kk++) {
      short8 b = *(const short8*)(W1p + ((ng * 4 + kk) * 64 + lane) * 8);
      acc = __builtin_amdgcn_mfma_f32_16x16x32_bf16(a[kk], b, acc, 0, 0, 0);
    }
    int col = ng * 16 + m;
#pragma unroll
    for (int r = 0; r < 4; r++) {
      h1[(r0 + quad * 4 + r) * HC + col] = f2bf(acc[r]);
    }
  }
}

// ---------------- attention logits layer1: als/ald [NN,4] ----------------
__global__ __launch_bounds__(256) void als1_kernel(const unsigned short* __restrict__ h1,
                                                   const float* __restrict__ a_src,
                                                   const float* __restrict__ a_dst,
                                                   float* __restrict__ als, float* __restrict__ ald) {
  int node = blockIdx.x * 4 + (threadIdx.x >> 6);
  int lane = threadIdx.x & 63;
  ushort4 hv4 = *(const ushort4*)(h1 + node * HC + lane * 4);
  float ps = 0.f, pd = 0.f;
  unsigned short hvv[4] = {hv4.x, hv4.y, hv4.z, hv4.w};
#pragma unroll
  for (int j = 0; j < 4; j++) {
    float hv = bf2f(hvv[j]);
    int ch = lane * 4 + j;
    ps += hv * a_src[ch];
    pd += hv * a_dst[ch];
  }
#pragma unroll
  for (int o = 1; o < 16; o <<= 1) { ps += __shfl_xor(ps, o, 64); pd += __shfl_xor(pd, o, 64); }
  if ((lane & 15) == 0) {
    int hh = lane >> 4;
    als[node * NHEAD + hh] = ps;
    ald[node * NHEAD + hh] = pd;
  }
}

// ---------------- edge histogram (deg by dst) + graph counts ----------------
__global__ void hist_kernel(const int* __restrict__ ei, const int* __restrict__ batch,
                            int* __restrict__ deg, int* __restrict__ counts) {
  int i = blockIdx.x * 256 + threadIdx.x;
  if (i < NE) atomicAdd(&deg[ei[NE + i]], 1);
  if (i < NN) atomicAdd(&counts[batch[i]], 1);
}

// ---------------- exclusive scan of deg -> off, cursor ----------------
__global__ void scan_a(const int* __restrict__ deg, int* __restrict__ bsum) {
  __shared__ int sm[256];
  int t = threadIdx.x, i = blockIdx.x * 256 + t;
  sm[t] = (i < NN) ? deg[i] : 0;
  __syncthreads();
  for (int s = 128; s > 0; s >>= 1) {
    if (t < s) sm[t] += sm[t + s];
    __syncthreads();
  }
  if (t == 0) bsum[blockIdx.x] = sm[0];
}
__global__ void scan_b(const int* __restrict__ bsum, int* __restrict__ bscan) {
  __shared__ int sm[256];
  int t = threadIdx.x;
  int own = (t < NB) ? bsum[t] : 0;
  sm[t] = own;
  __syncthreads();
  for (int s = 1; s < 256; s <<= 1) {
    int v = (t >= s) ? sm[t - s] : 0;
    __syncthreads();
    sm[t] += v;
    __syncthreads();
  }
  if (t < NB) bscan[t] = sm[t] - own;  // exclusive over block sums
}
__global__ void scan_c(const int* __restrict__ deg, const int* __restrict__ bscan,
                       int* __restrict__ off, int* __restrict__ cursor) {
  __shared__ int sm[256];
  int t = threadIdx.x, i = blockIdx.x * 256 + t;
  int d = (i < NN) ? deg[i] : 0;
  sm[t] = d;
  __syncthreads();
  for (int s = 1; s < 256; s <<= 1) {
    int v = (t >= s) ? sm[t - s] : 0;
    __syncthreads();
    sm[t] += v;
    __syncthreads();
  }
  int excl = bscan[blockIdx.x] + sm[t] - d;
  if (i < NN) {
    off[i] = excl;
    cursor[i] = excl;
    if (i == NN - 1) off[NN] = excl + d;
  }
}

// ---------------- scatter edges into CSR buckets (src + dst per slot) ----------------
__global__ void scatter_kernel(const int* __restrict__ ei, int* __restrict__ cursor,
                               int* __restrict__ esrc, int* __restrict__ edst) {
  int e = blockIdx.x * 256 + threadIdx.x;
  if (e >= NE) return;
  int d = ei[NE + e];
  int p = atomicAdd(&cursor[d], 1);
  esrc[p] = ei[e];
  edst[p] = d;
}

// ---------------- edge weights layer1: w = exp(lrelu(als[s]+ald[d])) per head --------
__global__ void ew1_kernel(const int* __restrict__ esrc, const int* __restrict__ edst,
                           const float* __restrict__ als, const float* __restrict__ ald,
                           float* __restrict__ ew) {
  int k = blockIdx.x * 256 + threadIdx.x;
  if (k >= NE) return;
  int s = esrc[k], d = edst[k];
  float4 as = *(const float4*)(als + s * 4);
  float4 ad = *(const float4*)(ald + d * 4);
  float4 w;
  w.x = __expf(lrelu(as.x + ad.x));
  w.y = __expf(lrelu(as.y + ad.y));
  w.z = __expf(lrelu(as.z + ad.z));
  w.w = __expf(lrelu(as.w + ad.w));
  *(float4*)(ew + k * 4) = w;
}

// ---------------- GAT layer1 aggregation: weighted gather, wave per (node,head) ------
__global__ __launch_bounds__(256) void agg1_kernel(const unsigned short* __restrict__ h1,
                                                   const float* __restrict__ als,
                                                   const float* __restrict__ ald,
                                                   const int* __restrict__ off,
                                                   const int* __restrict__ esrc,
                                                   const float* __restrict__ ew,
                                                   const float* __restrict__ b1,
                                                   unsigned short* __restrict__ out1) {
  int node = blockIdx.x;
  int hh = threadIdx.x >> 6, lane = threadIdx.x & 63;
  int ch = hh * CDIM + lane;
  int beg = off[node], end = off[node + 1];
  float acc0 = 0.f, acc1 = 0.f, zz0 = 0.f, zz1 = 0.f;
  int k = beg;
  for (; k + 1 < end; k += 2) {
    int s0 = esrc[k], s1 = esrc[k + 1];
    float w0 = ew[k * 4 + hh], w1 = ew[(k + 1) * 4 + hh];
    float hv0 = bf2f(h1[s0 * HC + ch]);
    float hv1 = bf2f(h1[s1 * HC + ch]);
    acc0 += w0 * hv0; zz0 += w0;
    acc1 += w1 * hv1; zz1 += w1;
  }
  if (k < end) {
    int s0 = esrc[k];
    float w0 = ew[k * 4 + hh];
    acc0 += w0 * bf2f(h1[s0 * HC + ch]);
    zz0 += w0;
  }
  float acc = acc0 + acc1, zz = zz0 + zz1;
  // self-loop
  float sw = __expf(lrelu(als[node * NHEAD + hh] + ald[node * NHEAD + hh]));
  acc += sw * bf2f(h1[node * HC + ch]);
  zz += sw;
  out1[node * HC + ch] = f2bf(acc / zz + b1[ch]);
}

// ---------------- BN stats over out1 ----------------
__global__ __launch_bounds__(256) void bnstats_kernel(const unsigned short* __restrict__ out1,
                                                      float* __restrict__ bnsum,
                                                      float* __restrict__ bnsumsq) {
  int t = threadIdx.x;
  float s = 0.f, s2 = 0.f;
  for (int r = blockIdx.x; r < NN; r += gridDim.x) {
    float v = bf2f(out1[r * HC + t]);
    s += v;
    s2 += v * v;
  }
  atomicAdd(&bnsum[t], s);
  atomicAdd(&bnsumsq[t], s2);
}
__global__ void bnfin_kernel(const float* __restrict__ bnsum, const float* __restrict__ bnsumsq,
                             const float* __restrict__ gamma, const float* __restrict__ beta,
                             float* __restrict__ scale, float* __restrict__ shift) {
  int t = threadIdx.x;
  float mu = bnsum[t] / (float)NN;
  float var = bnsumsq[t] / (float)NN - mu * mu;
  float sc = gamma[t] * rsqrtf(var + 1e-5f);
  scale[t] = sc;
  shift[t] = beta[t] - mu * sc;
}

// ---------------- GEMM2: h2 = relu(bn(out1)) @ W2  (bf16 MFMA, BN fused on A) --------
__global__ __launch_bounds__(256) void gemm2_kernel(const unsigned short* __restrict__ out1,
                                                    const unsigned short* __restrict__ W2p,
                                                    const float* __restrict__ scale,
                                                    const float* __restrict__ shift,
                                                    unsigned short* __restrict__ h2) {
  int wave = threadIdx.x >> 6, lane = threadIdx.x & 63;
  int tile = blockIdx.x * 4 + wave;
  if (tile >= NT1) return;
  int r0 = tile * 16, m = lane & 15, quad = lane >> 4;
  int row = r0 + m;
  short8 a[8];
#pragma unroll
  for (int kk = 0; kk < 8; kk++) {
    int kb = kk * 32 + quad * 8;
    short8 raw = *(const short8*)(out1 + row * HC + kb);
    float4 sc0 = *(const float4*)(scale + kb), sc1 = *(const float4*)(scale + kb + 4);
    float4 sh0 = *(const float4*)(shift + kb), sh1 = *(const float4*)(shift + kb + 4);
    alignas(16) unsigned short tmp[8];
    tmp[0] = f2bf(relu(bf2f((unsigned short)raw[0]) * sc0.x + sh0.x));
    tmp[1] = f2bf(relu(bf2f((unsigned short)raw[1]) * sc0.y + sh0.y));
    tmp[2] = f2bf(relu(bf2f((unsigned short)raw[2]) * sc0.z + sh0.z));
    tmp[3] = f2bf(relu(bf2f((unsigned short)raw[3]) * sc0.w + sh0.w));
    tmp[4] = f2bf(relu(bf2f((unsigned short)raw[4]) * sc1.x + sh1.x));
    tmp[5] = f2bf(relu(bf2f((unsigned short)raw[5]) * sc1.y + sh1.y));
    tmp[6] = f2bf(relu(bf2f((unsigned short)raw[6]) * sc1.z + sh1.z));
    tmp[7] = f2bf(relu(bf2f((unsigned short)raw[7]) * sc1.w + sh1.w));
    a[kk] = *(const short8*)tmp;
  }
#pragma unroll
  for (int ng = 0; ng < 4; ng++) {
    f32x4 acc = {0.f, 0.f, 0.f, 0.f};
#pragma unroll
    for (int kk = 0; kk < 8; kk++) {
      short8 b = *(const short8*)(W2p + ((ng * 8 + kk) * 64 + lane) * 8);
      acc = __builtin_amdgcn_mfma_f32_16x16x32_bf16(a[kk], b, acc, 0, 0, 0);
    }
    int col = ng * 16 + m;
#pragma unroll
    for (int r = 0; r < 4; r++) {
      h2[(r0 + quad * 4 + r) * CDIM + col] = f2bf(acc[r]);
    }
  }
}

// ---------------- attention logits layer2 ----------------
__global__ __launch_bounds__(256) void als2_kernel(const unsigned short* __restrict__ h2,
                                                   const float* __restrict__ a_src2,
                                                   const float* __restrict__ a_dst2,
                                                   float* __restrict__ als2, float* __restrict__ ald2) {
  int node = blockIdx.x * 4 + (threadIdx.x >> 6);
  int lane = threadIdx.x & 63;
  float hv = bf2f(h2[node * CDIM + lane]);
  float ps = hv * a_src2[lane];
  float pd = hv * a_dst2[lane];
#pragma unroll
  for (int o = 1; o < 64; o <<= 1) { ps += __shfl_xor(ps, o, 64); pd += __shfl_xor(pd, o, 64); }
  if (lane == 0) { als2[node] = ps; ald2[node] = pd; }
}

// ---------------- edge weights layer2 ----------------
__global__ void ew2_kernel(const int* __restrict__ esrc, const int* __restrict__ edst,
                           const float* __restrict__ als2, const float* __restrict__ ald2,
                           float* __restrict__ ew2) {
  int k = blockIdx.x * 256 + threadIdx.x;
  if (k >= NE) return;
  ew2[k] = __expf(lrelu(als2[esrc[k]] + ald2[edst[k]]));
}

// ---------------- GAT layer2 aggregation + ReLU + graph pooling (sum) ----------------
__global__ __launch_bounds__(256) void agg2_kernel(const unsigned short* __restrict__ h2,
                                                   const float* __restrict__ als2,
                                                   const float* __restrict__ ald2,
                                                   const int* __restrict__ off,
                                                   const int* __restrict__ esrc,
                                                   const float* __restrict__ ew2,
                                                   const float* __restrict__ b2,
                                                   const int* __restrict__ batch,
                                                   float* __restrict__ pooled) {
  int node = blockIdx.x * 4 + (threadIdx.x >> 6);
  int lane = threadIdx.x & 63;
  int beg = off[node], end = off[node + 1];
  float acc0 = 0.f, acc1 = 0.f, zz0 = 0.f, zz1 = 0.f;
  int k = beg;
  for (; k + 1 < end; k += 2) {
    int s0 = esrc[k], s1 = esrc[k + 1];
    float w0 = ew2[k], w1 = ew2[k + 1];
    acc0 += w0 * bf2f(h2[s0 * CDIM + lane]); zz0 += w0;
    acc1 += w1 * bf2f(h2[s1 * CDIM + lane]); zz1 += w1;
  }
  if (k < end) {
    int s0 = esrc[k];
    float w0 = ew2[k];
    acc0 += w0 * bf2f(h2[s0 * CDIM + lane]);
    zz0 += w0;
  }
  float acc = acc0 + acc1, zz = zz0 + zz1;
  float sw = __expf(lrelu(als2[node] + ald2[node]));
  acc += sw * bf2f(h2[node * CDIM + lane]);
  zz += sw;
  float v = relu(acc / zz + b2[lane]);
  atomicAdd(&pooled[batch[node] * CDIM + lane], v);
}

// ---------------- pooled mean + classifier (f32 output) ----------------
__global__ void cls_kernel(const float* __restrict__ pooled, const int* __restrict__ counts,
                           const float* __restrict__ cW1, const float* __restrict__ cb1,
                           const float* __restrict__ cW2, const float* __restrict__ cb2,
                           float* __restrict__ out) {
  __shared__ float p[64];
  __shared__ float z[32];
  int g = blockIdx.x, t = threadIdx.x;
  int c = counts[g];
  float cnt = (float)(c > 0 ? c : 1);
  p[t] = pooled[g * CDIM + t] / cnt;
  __syncthreads();
  if (t < 32) {
    float a = cb1[t];
    for (int k = 0; k < 64; k++) a += p[k] * cW1[k * 32 + t];
    z[t] = relu(a);
  }
  __syncthreads();
  if (t < NCLS) {
    float a = cb2[t];
    for (int k = 0; k < 32; k++) a += z[k] * cW2[k * NCLS + t];
    out[g * NCLS + t] = a;
  }
}

extern "C" void kernel_launch(void* const* d_in, const int* in_sizes, int n_in,
                              void* d_out, int out_size, void* d_ws, size_t ws_size,
                              hipStream_t stream) {
  const float* x = (const float*)d_in[0];
  const int* edge_index = (const int*)d_in[1];
  const int* batch = (const int*)d_in[2];
  const float* W1 = (const float*)d_in[3];
  const float* a_src1 = (const float*)d_in[4];
  const float* a_dst1 = (const float*)d_in[5];
  const float* b1 = (const float*)d_in[6];
  const float* gamma = (const float*)d_in[7];
  const float* beta = (const float*)d_in[8];
  const float* W2 = (const float*)d_in[9];
  const float* a_src2 = (const float*)d_in[10];
  const float* a_dst2 = (const float*)d_in[11];
  const float* b2 = (const float*)d_in[12];
  const float* cW1 = (const float*)d_in[13];
  const float* cb1 = (const float*)d_in[14];
  const float* cW2 = (const float*)d_in[15];
  const float* cb2 = (const float*)d_in[16];

  // ---- workspace layout ----
  // zero region (contiguous, zeroed every call): deg | bnsum | bnsumsq | pooled | counts
  int* deg = (int*)d_ws;
  float* bnsum = (float*)(deg + NN);
  float* bnsumsq = bnsum + HC;
  float* pooled = bnsumsq + HC;
  int* counts = (int*)(pooled + NGRAPH * CDIM);
  const int ZWORDS = NN + HC + HC + NGRAPH * CDIM + NGRAPH;
  char* p = (char*)(counts + NGRAPH);
  auto align256 = [&](char*& q) {
    size_t a = (size_t)(q - (char*)d_ws);
    a = (a + 255) & ~(size_t)255;
    q = (char*)d_ws + a;
  };
  align256(p);
  int* offs = (int*)p;            p += (size_t)(NN + 1) * 4; align256(p);
  int* cursor = (int*)p;          p += (size_t)NN * 4;       align256(p);
  int* esrc = (int*)p;            p += (size_t)NE * 4;       align256(p);
  int* edst = (int*)p;            p += (size_t)NE * 4;       align256(p);
  int* bsum = (int*)p;            p += 256 * 4;              align256(p);
  int* bscan = (int*)p;           p += 256 * 4;              align256(p);
  // h1 region; ew2 (NE*4 = 3.2MB) aliases its head: h1 dead after agg1, ew2 written later
  unsigned short* h1 = (unsigned short*)p;
  float* ew2 = (float*)p;         p += (size_t)NN * HC * 2;   align256(p);
  unsigned short* out1 = (unsigned short*)p; p += (size_t)NN * HC * 2;   align256(p);
  unsigned short* h2 = (unsigned short*)p;   p += (size_t)NN * CDIM * 2; align256(p);
  float* als1 = (float*)p;        p += (size_t)NN * NHEAD * 4; align256(p);
  float* ald1 = (float*)p;        p += (size_t)NN * NHEAD * 4; align256(p);
  float* als2v = (float*)p;       p += (size_t)NN * 4;         align256(p);
  float* ald2v = (float*)p;       p += (size_t)NN * 4;         align256(p);
  float* bnscale = (float*)p;     p += HC * 4;                 align256(p);
  float* bnshift = (float*)p;     p += HC * 4;                 align256(p);
  // xb (NN*DIN bf16 = 12.8MB); ew1 (NE*4 f32 = 12.8MB) aliases it: xb dead after gemm1
  unsigned short* xb = (unsigned short*)p;
  float* ew1 = (float*)p;         p += (size_t)NN * DIN * 2;   align256(p);
  unsigned short* W1p = (unsigned short*)p; p += 32768 * 2;    align256(p);
  unsigned short* W2p = (unsigned short*)p; p += 16384 * 2;    align256(p);

  zero_kernel<<<(ZWORDS + 255) / 256, 256, 0, stream>>>((int*)d_ws, ZWORDS);
  cvt_x_kernel<<<NN * DIN / 4 / 256, 256, 0, stream>>>(x, xb);
  repack_kernel<<<192, 256, 0, stream>>>(W1, W2, W1p, W2p);
  gemm1_kernel<<<(NT1 + 3) / 4, 256, 0, stream>>>(xb, W1p, h1);
  als1_kernel<<<NN / 4, 256, 0, stream>>>(h1, a_src1, a_dst1, als1, ald1);
  hist_kernel<<<(NE + 255) / 256, 256, 0, stream>>>(edge_index, batch, deg, counts);
  scan_a<<<NB, 256, 0, stream>>>(deg, bsum);
  scan_b<<<1, 256, 0, stream>>>(bsum, bscan);
  scan_c<<<NB, 256, 0, stream>>>(deg, bscan, offs, cursor);
  scatter_kernel<<<(NE + 255) / 256, 256, 0, stream>>>(edge_index, cursor, esrc, edst);
  ew1_kernel<<<(NE + 255) / 256, 256, 0, stream>>>(esrc, edst, als1, ald1, ew1);
  agg1_kernel<<<NN, 256, 0, stream>>>(h1, als1, ald1, offs, esrc, ew1, b1, out1);
  bnstats_kernel<<<1024, 256, 0, stream>>>(out1, bnsum, bnsumsq);
  bnfin_kernel<<<1, 256, 0, stream>>>(bnsum, bnsumsq, gamma, beta, bnscale, bnshift);
  gemm2_kernel<<<(NT1 + 3) / 4, 256, 0, stream>>>(out1, W2p, bnscale, bnshift, h2);
  als2_kernel<<<NN / 4, 256, 0, stream>>>(h2, a_src2, a_dst2, als2v, ald2v);
  ew2_kernel<<<(NE + 255) / 256, 256, 0, stream>>>(esrc, edst, als2v, ald2v, ew2);
  agg2_kernel<<<NN / 4, 256, 0, stream>>>(h2, als2v, ald2v, offs, esrc, ew2, b2, batch, pooled);
  cls_kernel<<<NGRAPH, 64, 0, stream>>>(pooled, counts, cW1, cb1, cW2, cb2, (float*)d_out);
}

// Round 7
// 418.738 us; speedup vs baseline: 2.1119x; 1.1935x over previous
//
#include <hip/hip_runtime.h>
#include <hip/hip_bf16.h>

#define NN 50000
#define NE 800000
#define DIN 128
#define HC 256
#define NHEAD 4
#define CDIM 64
#define NGRAPH 512
#define NCLS 10
#define NEG_SLOPE 0.2f
#define NB 196   // ceil(NN/256)
#define NT1 3125 // NN/16 M-tiles

typedef __hip_bfloat16 bf16;
typedef __attribute__((ext_vector_type(8))) short short8;
typedef __attribute__((ext_vector_type(4))) float f32x4;

__device__ __forceinline__ float bf2f(unsigned short u) {
  union { unsigned int i; float f; } x;
  x.i = ((unsigned int)u) << 16;
  return x.f;
}
__device__ __forceinline__ unsigned short f2bf(float f) {
  bf16 v = __float2bfloat16(f);
  union { bf16 b; unsigned short s; } x;
  x.b = v;
  return x.s;
}
__device__ __forceinline__ float lrelu(float x) { return x >= 0.f ? x : NEG_SLOPE * x; }
// NaN-propagating relu (fmaxf would silently clamp NaN to 0)
__device__ __forceinline__ float relu(float x) { return x < 0.f ? 0.f : x; }

// ---------------- zero scratch accumulators ----------------
__global__ void zero_kernel(int* __restrict__ p, int n) {
  int i = blockIdx.x * 256 + threadIdx.x;
  if (i < n) p[i] = 0;
}

// ---------------- repack W1,W2 (f32) into MFMA B-frag bf16 order ----------------
// B frag for 16x16x32: lane holds col n = lane&15, k = (lane>>4)*8 + j, j=0..7
__global__ void repack_kernel(const float* __restrict__ W1, const float* __restrict__ W2,
                              unsigned short* __restrict__ W1p, unsigned short* __restrict__ W2p) {
  int i = blockIdx.x * 256 + threadIdx.x;
  if (i < 16 * 4 * 64 * 8) {  // W1: [128,256] -> ng(16) kk(4) lane(64) j(8)
    int j = i & 7, lane = (i >> 3) & 63, kk = (i >> 9) & 3, ng = i >> 11;
    int n = ng * 16 + (lane & 15);
    int k = kk * 32 + (lane >> 4) * 8 + j;
    W1p[i] = f2bf(W1[k * HC + n]);
  }
  int i2 = i - 16 * 4 * 64 * 8;
  if (i2 >= 0 && i2 < 4 * 8 * 64 * 8) {  // W2: [256,64] -> ng(4) kk(8) lane(64) j(8)
    int j = i2 & 7, lane = (i2 >> 3) & 63, kk = (i2 >> 9) & 7, ng = i2 >> 12;
    int n = ng * 16 + (lane & 15);
    int k = kk * 32 + (lane >> 4) * 8 + j;
    W2p[i2] = f2bf(W2[k * CDIM + n]);
  }
}

// ---------------- GEMM1: h1[NN,256] = bf16(x[NN,128]) @ W1  (bf16 MFMA) -------------
// f32->bf16 conversion of x fused into A-fragment load.
__global__ __launch_bounds__(256) void gemm1_kernel(const float* __restrict__ x,
                                                    const unsigned short* __restrict__ W1p,
                                                    unsigned short* __restrict__ h1) {
  int wave = threadIdx.x >> 6, lane = threadIdx.x & 63;
  int tile = blockIdx.x * 4 + wave;
  if (tile >= NT1) return;
  int r0 = tile * 16, m = lane & 15, quad = lane >> 4;
  int row = r0 + m;
  short8 a[4];
#pragma unroll
  for (int kk = 0; kk < 4; kk++) {
    int kb = kk * 32 + quad * 8;
    float4 f0 = *(const float4*)(x + row * DIN + kb);
    float4 f1 = *(const float4*)(x + row * DIN + kb + 4);
    alignas(16) unsigned short tmp[8];
    tmp[0] = f2bf(f0.x); tmp[1] = f2bf(f0.y); tmp[2] = f2bf(f0.z); tmp[3] = f2bf(f0.w);
    tmp[4] = f2bf(f1.x); tmp[5] = f2bf(f1.y); tmp[6] = f2bf(f1.z); tmp[7] = f2bf(f1.w);
    a[kk] = *(const short8*)tmp;
  }
#pragma unroll
  for (int ng = 0; ng < 16; ng++) {
    f32x4 acc = {0.f, 0.f, 0.f, 0.f};
#pragma unroll
    for (int kk = 0; kk < 4; kk++) {
      short8 b = *(const short8*)(W1p + ((ng * 4 + kk) * 64 + lane) * 8);
      acc = __builtin_amdgcn_mfma_f32_16x16x32_bf16(a[kk], b, acc, 0, 0, 0);
    }
    int col = ng * 16 + m;
#pragma unroll
    for (int r = 0; r < 4; r++) {
      h1[(r0 + quad * 4 + r) * HC + col] = f2bf(acc[r]);
    }
  }
}

// ---------------- attention logits layer1: als/ald [NN,4] ----------------
__global__ __launch_bounds__(256) void als1_kernel(const unsigned short* __restrict__ h1,
                                                   const float* __restrict__ a_src,
                                                   const float* __restrict__ a_dst,
                                                   float* __restrict__ als, float* __restrict__ ald) {
  int node = blockIdx.x * 4 + (threadIdx.x >> 6);
  int lane = threadIdx.x & 63;
  ushort4 hv4 = *(const ushort4*)(h1 + node * HC + lane * 4);
  float ps = 0.f, pd = 0.f;
  unsigned short hvv[4] = {hv4.x, hv4.y, hv4.z, hv4.w};
#pragma unroll
  for (int j = 0; j < 4; j++) {
    float hv = bf2f(hvv[j]);
    int ch = lane * 4 + j;
    ps += hv * a_src[ch];
    pd += hv * a_dst[ch];
  }
#pragma unroll
  for (int o = 1; o < 16; o <<= 1) { ps += __shfl_xor(ps, o, 64); pd += __shfl_xor(pd, o, 64); }
  if ((lane & 15) == 0) {
    int hh = lane >> 4;
    als[node * NHEAD + hh] = ps;
    ald[node * NHEAD + hh] = pd;
  }
}

// ---------------- edge histogram (deg by dst) + graph counts ----------------
__global__ void hist_kernel(const int* __restrict__ ei, const int* __restrict__ batch,
                            int* __restrict__ deg, int* __restrict__ counts) {
  int i = blockIdx.x * 256 + threadIdx.x;
  if (i < NE) atomicAdd(&deg[ei[NE + i]], 1);
  if (i < NN) atomicAdd(&counts[batch[i]], 1);
}

// ---------------- exclusive scan of deg -> off, cursor ----------------
__global__ void scan_a(const int* __restrict__ deg, int* __restrict__ bsum) {
  __shared__ int sm[256];
  int t = threadIdx.x, i = blockIdx.x * 256 + t;
  sm[t] = (i < NN) ? deg[i] : 0;
  __syncthreads();
  for (int s = 128; s > 0; s >>= 1) {
    if (t < s) sm[t] += sm[t + s];
    __syncthreads();
  }
  if (t == 0) bsum[blockIdx.x] = sm[0];
}
__global__ void scan_b(const int* __restrict__ bsum, int* __restrict__ bscan) {
  __shared__ int sm[256];
  int t = threadIdx.x;
  int own = (t < NB) ? bsum[t] : 0;
  sm[t] = own;
  __syncthreads();
  for (int s = 1; s < 256; s <<= 1) {
    int v = (t >= s) ? sm[t - s] : 0;
    __syncthreads();
    sm[t] += v;
    __syncthreads();
  }
  if (t < NB) bscan[t] = sm[t] - own;  // exclusive over block sums
}
__global__ void scan_c(const int* __restrict__ deg, const int* __restrict__ bscan,
                       int* __restrict__ off, int* __restrict__ cursor) {
  __shared__ int sm[256];
  int t = threadIdx.x, i = blockIdx.x * 256 + t;
  int d = (i < NN) ? deg[i] : 0;
  sm[t] = d;
  __syncthreads();
  for (int s = 1; s < 256; s <<= 1) {
    int v = (t >= s) ? sm[t - s] : 0;
    __syncthreads();
    sm[t] += v;
    __syncthreads();
  }
  int excl = bscan[blockIdx.x] + sm[t] - d;
  if (i < NN) {
    off[i] = excl;
    cursor[i] = excl;
    if (i == NN - 1) off[NN] = excl + d;
  }
}

// ---------------- scatter edges into CSR + fused layer1 edge weights ----------------
__global__ void scatter_kernel(const int* __restrict__ ei, int* __restrict__ cursor,
                               const float* __restrict__ als, const float* __restrict__ ald,
                               int* __restrict__ esrc, int* __restrict__ edst,
                               float* __restrict__ ew) {
  int e = blockIdx.x * 256 + threadIdx.x;
  if (e >= NE) return;
  int s = ei[e];
  int d = ei[NE + e];
  int p = atomicAdd(&cursor[d], 1);
  esrc[p] = s;
  edst[p] = d;
  float4 as = *(const float4*)(als + s * 4);
  float4 ad = *(const float4*)(ald + d * 4);
  float4 w;
  w.x = __expf(lrelu(as.x + ad.x));
  w.y = __expf(lrelu(as.y + ad.y));
  w.z = __expf(lrelu(as.z + ad.z));
  w.w = __expf(lrelu(as.w + ad.w));
  *(float4*)(ew + p * 4) = w;
}

// ---------------- GAT layer1 aggregation: wave per node, 8B/lane gathers -------------
// lane covers channels [lane*4, lane*4+4) -> all in head (lane>>4).
__global__ __launch_bounds__(256) void agg1_kernel(const unsigned short* __restrict__ h1,
                                                   const float* __restrict__ als,
                                                   const float* __restrict__ ald,
                                                   const int* __restrict__ off,
                                                   const int* __restrict__ esrc,
                                                   const float* __restrict__ ew,
                                                   const float* __restrict__ b1,
                                                   unsigned short* __restrict__ out1) {
  int node = blockIdx.x * 4 + (threadIdx.x >> 6);
  int lane = threadIdx.x & 63;
  int hh = lane >> 4;
  int c0 = lane * 4;
  int beg = off[node], end = off[node + 1];
  float a0 = 0.f, a1 = 0.f, a2 = 0.f, a3 = 0.f, zz = 0.f;
  int k = beg;
  for (; k + 3 < end; k += 4) {
    int s0 = esrc[k], s1 = esrc[k + 1], s2 = esrc[k + 2], s3 = esrc[k + 3];
    float w0 = ew[k * 4 + hh], w1 = ew[(k + 1) * 4 + hh];
    float w2 = ew[(k + 2) * 4 + hh], w3 = ew[(k + 3) * 4 + hh];
    ushort4 v0 = *(const ushort4*)(h1 + s0 * HC + c0);
    ushort4 v1 = *(const ushort4*)(h1 + s1 * HC + c0);
    ushort4 v2 = *(const ushort4*)(h1 + s2 * HC + c0);
    ushort4 v3 = *(const ushort4*)(h1 + s3 * HC + c0);
    a0 += w0 * bf2f(v0.x) + w1 * bf2f(v1.x) + w2 * bf2f(v2.x) + w3 * bf2f(v3.x);
    a1 += w0 * bf2f(v0.y) + w1 * bf2f(v1.y) + w2 * bf2f(v2.y) + w3 * bf2f(v3.y);
    a2 += w0 * bf2f(v0.z) + w1 * bf2f(v1.z) + w2 * bf2f(v2.z) + w3 * bf2f(v3.z);
    a3 += w0 * bf2f(v0.w) + w1 * bf2f(v1.w) + w2 * bf2f(v2.w) + w3 * bf2f(v3.w);
    zz += w0 + w1 + w2 + w3;
  }
  for (; k < end; k++) {
    int s0 = esrc[k];
    float w0 = ew[k * 4 + hh];
    ushort4 v0 = *(const ushort4*)(h1 + s0 * HC + c0);
    a0 += w0 * bf2f(v0.x);
    a1 += w0 * bf2f(v0.y);
    a2 += w0 * bf2f(v0.z);
    a3 += w0 * bf2f(v0.w);
    zz += w0;
  }
  // self-loop
  float sw = __expf(lrelu(als[node * NHEAD + hh] + ald[node * NHEAD + hh]));
  ushort4 vs = *(const ushort4*)(h1 + node * HC + c0);
  a0 += sw * bf2f(vs.x);
  a1 += sw * bf2f(vs.y);
  a2 += sw * bf2f(vs.z);
  a3 += sw * bf2f(vs.w);
  zz += sw;
  float inv = 1.f / zz;
  float4 bb = *(const float4*)(b1 + c0);
  ushort4 o;
  o.x = f2bf(a0 * inv + bb.x);
  o.y = f2bf(a1 * inv + bb.y);
  o.z = f2bf(a2 * inv + bb.z);
  o.w = f2bf(a3 * inv + bb.w);
  *(ushort4*)(out1 + node * HC + c0) = o;
}

// ---------------- BN stats over out1 ----------------
__global__ __launch_bounds__(256) void bnstats_kernel(const unsigned short* __restrict__ out1,
                                                      float* __restrict__ bnsum,
                                                      float* __restrict__ bnsumsq) {
  int t = threadIdx.x;
  float s = 0.f, s2 = 0.f;
  for (int r = blockIdx.x; r < NN; r += gridDim.x) {
    float v = bf2f(out1[r * HC + t]);
    s += v;
    s2 += v * v;
  }
  atomicAdd(&bnsum[t], s);
  atomicAdd(&bnsumsq[t], s2);
}

// ---------------- GEMM2: h2 = relu(bn(out1)) @ W2  (bf16 MFMA, BN finalize inlined) --
__global__ __launch_bounds__(256) void gemm2_kernel(const unsigned short* __restrict__ out1,
                                                    const unsigned short* __restrict__ W2p,
                                                    const float* __restrict__ bnsum,
                                                    const float* __restrict__ bnsumsq,
                                                    const float* __restrict__ gamma,
                                                    const float* __restrict__ beta,
                                                    unsigned short* __restrict__ h2) {
  __shared__ float scale_s[HC], shift_s[HC];
  {
    int t = threadIdx.x;
    float mu = bnsum[t] / (float)NN;
    float var = bnsumsq[t] / (float)NN - mu * mu;
    float sc = gamma[t] * rsqrtf(var + 1e-5f);
    scale_s[t] = sc;
    shift_s[t] = beta[t] - mu * sc;
  }
  __syncthreads();
  int wave = threadIdx.x >> 6, lane = threadIdx.x & 63;
  int tile = blockIdx.x * 4 + wave;
  if (tile >= NT1) return;
  int r0 = tile * 16, m = lane & 15, quad = lane >> 4;
  int row = r0 + m;
  short8 a[8];
#pragma unroll
  for (int kk = 0; kk < 8; kk++) {
    int kb = kk * 32 + quad * 8;
    short8 raw = *(const short8*)(out1 + row * HC + kb);
    alignas(16) unsigned short tmp[8];
#pragma unroll
    for (int j = 0; j < 8; j++) {
      tmp[j] = f2bf(relu(bf2f((unsigned short)raw[j]) * scale_s[kb + j] + shift_s[kb + j]));
    }
    a[kk] = *(const short8*)tmp;
  }
#pragma unroll
  for (int ng = 0; ng < 4; ng++) {
    f32x4 acc = {0.f, 0.f, 0.f, 0.f};
#pragma unroll
    for (int kk = 0; kk < 8; kk++) {
      short8 b = *(const short8*)(W2p + ((ng * 8 + kk) * 64 + lane) * 8);
      acc = __builtin_amdgcn_mfma_f32_16x16x32_bf16(a[kk], b, acc, 0, 0, 0);
    }
    int col = ng * 16 + m;
#pragma unroll
    for (int r = 0; r < 4; r++) {
      h2[(r0 + quad * 4 + r) * CDIM + col] = f2bf(acc[r]);
    }
  }
}

// ---------------- attention logits layer2 ----------------
__global__ __launch_bounds__(256) void als2_kernel(const unsigned short* __restrict__ h2,
                                                   const float* __restrict__ a_src2,
                                                   const float* __restrict__ a_dst2,
                                                   float* __restrict__ als2, float* __restrict__ ald2) {
  int node = blockIdx.x * 4 + (threadIdx.x >> 6);
  int lane = threadIdx.x & 63;
  float hv = bf2f(h2[node * CDIM + lane]);
  float ps = hv * a_src2[lane];
  float pd = hv * a_dst2[lane];
#pragma unroll
  for (int o = 1; o < 64; o <<= 1) { ps += __shfl_xor(ps, o, 64); pd += __shfl_xor(pd, o, 64); }
  if (lane == 0) { als2[node] = ps; ald2[node] = pd; }
}

// ---------------- edge weights layer2 ----------------
__global__ void ew2_kernel(const int* __restrict__ esrc, const int* __restrict__ edst,
                           const float* __restrict__ als2, const float* __restrict__ ald2,
                           float* __restrict__ ew2) {
  int k = blockIdx.x * 256 + threadIdx.x;
  if (k >= NE) return;
  ew2[k] = __expf(lrelu(als2[esrc[k]] + ald2[edst[k]]));
}

// ---------------- GAT layer2 aggregation + ReLU + pooling: wave/node, 2 edges/iter ---
// lane covers channel pair (lane&31)*2 of edge k + (lane>>5).
__global__ __launch_bounds__(256) void agg2_kernel(const unsigned short* __restrict__ h2,
                                                   const float* __restrict__ als2,
                                                   const float* __restrict__ ald2,
                                                   const int* __restrict__ off,
                                                   const int* __restrict__ esrc,
                                                   const float* __restrict__ ew2,
                                                   const float* __restrict__ b2,
                                                   const int* __restrict__ batch,
                                                   float* __restrict__ pooled) {
  int node = blockIdx.x * 4 + (threadIdx.x >> 6);
  int lane = threadIdx.x & 63;
  int half = lane >> 5;
  int cp = (lane & 31) * 2;
  int beg = off[node], end = off[node + 1];
  float a0 = 0.f, a1 = 0.f, zz = 0.f;
  int k = beg;
  for (; k + 3 < end; k += 4) {
    int i0 = k + half, i1 = k + 2 + half;
    int s0 = esrc[i0], s1 = esrc[i1];
    float w0 = ew2[i0], w1 = ew2[i1];
    ushort2 v0 = *(const ushort2*)(h2 + s0 * CDIM + cp);
    ushort2 v1 = *(const ushort2*)(h2 + s1 * CDIM + cp);
    a0 += w0 * bf2f(v0.x) + w1 * bf2f(v1.x);
    a1 += w0 * bf2f(v0.y) + w1 * bf2f(v1.y);
    zz += w0 + w1;
  }
  for (; k < end; k += 2) {
    int i0 = k + half;
    if (i0 < end) {
      int s0 = esrc[i0];
      float w0 = ew2[i0];
      ushort2 v0 = *(const ushort2*)(h2 + s0 * CDIM + cp);
      a0 += w0 * bf2f(v0.x);
      a1 += w0 * bf2f(v0.y);
      zz += w0;
    }
  }
  // combine the two halves (lanes L and L^32 cover the same channel pair)
  a0 += __shfl_xor(a0, 32, 64);
  a1 += __shfl_xor(a1, 32, 64);
  zz += __shfl_xor(zz, 32, 64);
  if (half == 0) {
    float sw = __expf(lrelu(als2[node] + ald2[node]));
    ushort2 vs = *(const ushort2*)(h2 + node * CDIM + cp);
    a0 += sw * bf2f(vs.x);
    a1 += sw * bf2f(vs.y);
    zz += sw;
    float inv = 1.f / zz;
    int g = batch[node];
    float v0 = relu(a0 * inv + b2[cp]);
    float v1 = relu(a1 * inv + b2[cp + 1]);
    atomicAdd(&pooled[g * CDIM + cp], v0);
    atomicAdd(&pooled[g * CDIM + cp + 1], v1);
  }
}

// ---------------- pooled mean + classifier (f32 output) ----------------
__global__ void cls_kernel(const float* __restrict__ pooled, const int* __restrict__ counts,
                           const float* __restrict__ cW1, const float* __restrict__ cb1,
                           const float* __restrict__ cW2, const float* __restrict__ cb2,
                           float* __restrict__ out) {
  __shared__ float p[64];
  __shared__ float z[32];
  int g = blockIdx.x, t = threadIdx.x;
  int c = counts[g];
  float cnt = (float)(c > 0 ? c : 1);
  p[t] = pooled[g * CDIM + t] / cnt;
  __syncthreads();
  if (t < 32) {
    float a = cb1[t];
    for (int k = 0; k < 64; k++) a += p[k] * cW1[k * 32 + t];
    z[t] = relu(a);
  }
  __syncthreads();
  if (t < NCLS) {
    float a = cb2[t];
    for (int k = 0; k < 32; k++) a += z[k] * cW2[k * NCLS + t];
    out[g * NCLS + t] = a;
  }
}

extern "C" void kernel_launch(void* const* d_in, const int* in_sizes, int n_in,
                              void* d_out, int out_size, void* d_ws, size_t ws_size,
                              hipStream_t stream) {
  const float* x = (const float*)d_in[0];
  const int* edge_index = (const int*)d_in[1];
  const int* batch = (const int*)d_in[2];
  const float* W1 = (const float*)d_in[3];
  const float* a_src1 = (const float*)d_in[4];
  const float* a_dst1 = (const float*)d_in[5];
  const float* b1 = (const float*)d_in[6];
  const float* gamma = (const float*)d_in[7];
  const float* beta = (const float*)d_in[8];
  const float* W2 = (const float*)d_in[9];
  const float* a_src2 = (const float*)d_in[10];
  const float* a_dst2 = (const float*)d_in[11];
  const float* b2 = (const float*)d_in[12];
  const float* cW1 = (const float*)d_in[13];
  const float* cb1 = (const float*)d_in[14];
  const float* cW2 = (const float*)d_in[15];
  const float* cb2 = (const float*)d_in[16];

  // ---- workspace layout ----
  // zero region (contiguous, zeroed every call): deg | bnsum | bnsumsq | pooled | counts
  int* deg = (int*)d_ws;
  float* bnsum = (float*)(deg + NN);
  float* bnsumsq = bnsum + HC;
  float* pooled = bnsumsq + HC;
  int* counts = (int*)(pooled + NGRAPH * CDIM);
  const int ZWORDS = NN + HC + HC + NGRAPH * CDIM + NGRAPH;
  char* p = (char*)(counts + NGRAPH);
  auto align256 = [&](char*& q) {
    size_t a = (size_t)(q - (char*)d_ws);
    a = (a + 255) & ~(size_t)255;
    q = (char*)d_ws + a;
  };
  align256(p);
  int* offs = (int*)p;            p += (size_t)(NN + 1) * 4; align256(p);
  int* cursor = (int*)p;          p += (size_t)NN * 4;       align256(p);
  int* esrc = (int*)p;            p += (size_t)NE * 4;       align256(p);
  int* edst = (int*)p;            p += (size_t)NE * 4;       align256(p);
  int* bsum = (int*)p;            p += 256 * 4;              align256(p);
  int* bscan = (int*)p;           p += 256 * 4;              align256(p);
  // h1 region; ew2 (NE*4 = 3.2MB) aliases its head: h1 dead after agg1, ew2 written later
  unsigned short* h1 = (unsigned short*)p;
  float* ew2 = (float*)p;         p += (size_t)NN * HC * 2;   align256(p);
  unsigned short* out1 = (unsigned short*)p; p += (size_t)NN * HC * 2;   align256(p);
  unsigned short* h2 = (unsigned short*)p;   p += (size_t)NN * CDIM * 2; align256(p);
  float* als1 = (float*)p;        p += (size_t)NN * NHEAD * 4; align256(p);
  float* ald1 = (float*)p;        p += (size_t)NN * NHEAD * 4; align256(p);
  float* als2v = (float*)p;       p += (size_t)NN * 4;         align256(p);
  float* ald2v = (float*)p;       p += (size_t)NN * 4;         align256(p);
  float* ew1 = (float*)p;         p += (size_t)NE * NHEAD * 4; align256(p);
  unsigned short* W1p = (unsigned short*)p; p += 32768 * 2;    align256(p);
  unsigned short* W2p = (unsigned short*)p; p += 16384 * 2;    align256(p);

  zero_kernel<<<(ZWORDS + 255) / 256, 256, 0, stream>>>((int*)d_ws, ZWORDS);
  repack_kernel<<<192, 256, 0, stream>>>(W1, W2, W1p, W2p);
  gemm1_kernel<<<(NT1 + 3) / 4, 256, 0, stream>>>(x, W1p, h1);
  als1_kernel<<<NN / 4, 256, 0, stream>>>(h1, a_src1, a_dst1, als1, ald1);
  hist_kernel<<<(NE + 255) / 256, 256, 0, stream>>>(edge_index, batch, deg, counts);
  scan_a<<<NB, 256, 0, stream>>>(deg, bsum);
  scan_b<<<1, 256, 0, stream>>>(bsum, bscan);
  scan_c<<<NB, 256, 0, stream>>>(deg, bscan, offs, cursor);
  scatter_kernel<<<(NE + 255) / 256, 256, 0, stream>>>(edge_index, cursor, als1, ald1,
                                                       esrc, edst, ew1);
  agg1_kernel<<<NN / 4, 256, 0, stream>>>(h1, als1, ald1, offs, esrc, ew1, b1, out1);
  bnstats_kernel<<<1024, 256, 0, stream>>>(out1, bnsum, bnsumsq);
  gemm2_kernel<<<(NT1 + 3) / 4, 256, 0, stream>>>(out1, W2p, bnsum, bnsumsq, gamma, beta, h2);
  als2_kernel<<<NN / 4, 256, 0, stream>>>(h2, a_src2, a_dst2, als2v, ald2v);
  ew2_kernel<<<(NE + 255) / 256, 256, 0, stream>>>(esrc, edst, als2v, ald2v, ew2);
  agg2_kernel<<<NN / 4, 256, 0, stream>>>(h2, als2v, ald2v, offs, esrc, ew2, b2, batch, pooled);
  cls_kernel<<<NGRAPH, 64, 0, stream>>>(pooled, counts, cW1, cb1, cW2, cb2, (float*)d_out);
}

// Round 8
// 376.220 us; speedup vs baseline: 2.3506x; 1.1130x over previous
//
#include <hip/hip_runtime.h>
#include <hip/hip_bf16.h>

#define NN 50000
#define NE 800000
#define DIN 128
#define HC 256
#define NHEAD 4
#define CDIM 64
#define NGRAPH 512
#define NCLS 10
#define NEG_SLOPE 0.2f
#define NB 196   // ceil(NN/256)
#define NT1 3125 // NN/16 M-tiles

typedef __hip_bfloat16 bf16;
typedef __attribute__((ext_vector_type(8))) short short8;
typedef __attribute__((ext_vector_type(4))) float f32x4;

__device__ __forceinline__ float bf2f(unsigned short u) {
  union { unsigned int i; float f; } x;
  x.i = ((unsigned int)u) << 16;
  return x.f;
}
__device__ __forceinline__ unsigned short f2bf(float f) {
  bf16 v = __float2bfloat16(f);
  union { bf16 b; unsigned short s; } x;
  x.b = v;
  return x.s;
}
__device__ __forceinline__ float lrelu(float x) { return x >= 0.f ? x : NEG_SLOPE * x; }
// NaN-propagating relu (fmaxf would silently clamp NaN to 0)
__device__ __forceinline__ float relu(float x) { return x < 0.f ? 0.f : x; }

// ---------------- zero scratch accumulators ----------------
__global__ void zero_kernel(int* __restrict__ p, int n) {
  int i = blockIdx.x * 256 + threadIdx.x;
  if (i < n) p[i] = 0;
}

// ---------------- repack W1,W2 (f32) into MFMA B-frag bf16 order ----------------
__global__ void repack_kernel(const float* __restrict__ W1, const float* __restrict__ W2,
                              unsigned short* __restrict__ W1p, unsigned short* __restrict__ W2p) {
  int i = blockIdx.x * 256 + threadIdx.x;
  if (i < 16 * 4 * 64 * 8) {  // W1: [128,256] -> ng(16) kk(4) lane(64) j(8)
    int j = i & 7, lane = (i >> 3) & 63, kk = (i >> 9) & 3, ng = i >> 11;
    int n = ng * 16 + (lane & 15);
    int k = kk * 32 + (lane >> 4) * 8 + j;
    W1p[i] = f2bf(W1[k * HC + n]);
  }
  int i2 = i - 16 * 4 * 64 * 8;
  if (i2 >= 0 && i2 < 4 * 8 * 64 * 8) {  // W2: [256,64] -> ng(4) kk(8) lane(64) j(8)
    int j = i2 & 7, lane = (i2 >> 3) & 63, kk = (i2 >> 9) & 7, ng = i2 >> 12;
    int n = ng * 16 + (lane & 15);
    int k = kk * 32 + (lane >> 4) * 8 + j;
    W2p[i2] = f2bf(W2[k * CDIM + n]);
  }
}

// ---------------- GEMM1 + fused als1/ald1: h1 = bf16(x) @ W1  (bf16 MFMA) ------------
// C/D layout: col=lane&15 (within ng tile), row=quad*4+r. Head of col = ng>>2.
// als1[row,h] = sum_col h[row,col]*a_src[col] computed from f32 acc, reduced over m-lanes.
__global__ __launch_bounds__(256) void gemm1_kernel(const float* __restrict__ x,
                                                    const unsigned short* __restrict__ W1p,
                                                    const float* __restrict__ a_src,
                                                    const float* __restrict__ a_dst,
                                                    unsigned short* __restrict__ h1,
                                                    float* __restrict__ als,
                                                    float* __restrict__ ald) {
  __shared__ float sh_as[HC], sh_ad[HC];
  {
    int t = threadIdx.x;
    sh_as[t] = a_src[t];
    sh_ad[t] = a_dst[t];
  }
  __syncthreads();
  int wave = threadIdx.x >> 6, lane = threadIdx.x & 63;
  int tile = blockIdx.x * 4 + wave;
  if (tile >= NT1) return;
  int r0 = tile * 16, m = lane & 15, quad = lane >> 4;
  int row = r0 + m;
  short8 a[4];
#pragma unroll
  for (int kk = 0; kk < 4; kk++) {
    int kb = kk * 32 + quad * 8;
    float4 f0 = *(const float4*)(x + row * DIN + kb);
    float4 f1 = *(const float4*)(x + row * DIN + kb + 4);
    alignas(16) unsigned short tmp[8];
    tmp[0] = f2bf(f0.x); tmp[1] = f2bf(f0.y); tmp[2] = f2bf(f0.z); tmp[3] = f2bf(f0.w);
    tmp[4] = f2bf(f1.x); tmp[5] = f2bf(f1.y); tmp[6] = f2bf(f1.z); tmp[7] = f2bf(f1.w);
    a[kk] = *(const short8*)tmp;
  }
#pragma unroll
  for (int hg = 0; hg < 4; hg++) {
    float ps[4] = {0.f, 0.f, 0.f, 0.f};
    float pd[4] = {0.f, 0.f, 0.f, 0.f};
#pragma unroll
    for (int sub = 0; sub < 4; sub++) {
      int ng = hg * 4 + sub;
      f32x4 acc = {0.f, 0.f, 0.f, 0.f};
#pragma unroll
      for (int kk = 0; kk < 4; kk++) {
        short8 b = *(const short8*)(W1p + ((ng * 4 + kk) * 64 + lane) * 8);
        acc = __builtin_amdgcn_mfma_f32_16x16x32_bf16(a[kk], b, acc, 0, 0, 0);
      }
      int col = ng * 16 + m;
      float asv = sh_as[col], adv = sh_ad[col];
#pragma unroll
      for (int r = 0; r < 4; r++) {
        h1[(r0 + quad * 4 + r) * HC + col] = f2bf(acc[r]);
        ps[r] += acc[r] * asv;
        pd[r] += acc[r] * adv;
      }
    }
    // reduce over the 16 m-lanes within each quad
#pragma unroll
    for (int o = 1; o < 16; o <<= 1) {
#pragma unroll
      for (int r = 0; r < 4; r++) {
        ps[r] += __shfl_xor(ps[r], o, 64);
        pd[r] += __shfl_xor(pd[r], o, 64);
      }
    }
    if (m == 0) {
#pragma unroll
      for (int r = 0; r < 4; r++) {
        int rr = r0 + quad * 4 + r;
        als[rr * NHEAD + hg] = ps[r];
        ald[rr * NHEAD + hg] = pd[r];
      }
    }
  }
}

// ---------------- edge histogram (deg by dst, 4-way sharded) ----------------
__global__ void hist_kernel(const int* __restrict__ ei, int* __restrict__ deg4) {
  int i = blockIdx.x * 256 + threadIdx.x;
  if (i < NE) atomicAdd(&deg4[(i & 3) * NN + ei[NE + i]], 1);
}

// ---------------- exclusive scan of deg -> off, cursor ----------------
__global__ void scan_a(const int* __restrict__ deg4, int* __restrict__ bsum,
                       int* __restrict__ degsum) {
  __shared__ int sm[256];
  int t = threadIdx.x, i = blockIdx.x * 256 + t;
  int d = 0;
  if (i < NN) {
    d = deg4[i] + deg4[NN + i] + deg4[2 * NN + i] + deg4[3 * NN + i];
    degsum[i] = d;
  }
  sm[t] = d;
  __syncthreads();
  for (int s = 128; s > 0; s >>= 1) {
    if (t < s) sm[t] += sm[t + s];
    __syncthreads();
  }
  if (t == 0) bsum[blockIdx.x] = sm[0];
}
__global__ void scan_b(const int* __restrict__ bsum, int* __restrict__ bscan) {
  __shared__ int sm[256];
  int t = threadIdx.x;
  int own = (t < NB) ? bsum[t] : 0;
  sm[t] = own;
  __syncthreads();
  for (int s = 1; s < 256; s <<= 1) {
    int v = (t >= s) ? sm[t - s] : 0;
    __syncthreads();
    sm[t] += v;
    __syncthreads();
  }
  if (t < NB) bscan[t] = sm[t] - own;  // exclusive over block sums
}
__global__ void scan_c(const int* __restrict__ degsum, const int* __restrict__ bscan,
                       int* __restrict__ off, int* __restrict__ cursor) {
  __shared__ int sm[256];
  int t = threadIdx.x, i = blockIdx.x * 256 + t;
  int d = (i < NN) ? degsum[i] : 0;
  sm[t] = d;
  __syncthreads();
  for (int s = 1; s < 256; s <<= 1) {
    int v = (t >= s) ? sm[t - s] : 0;
    __syncthreads();
    sm[t] += v;
    __syncthreads();
  }
  int excl = bscan[blockIdx.x] + sm[t] - d;
  if (i < NN) {
    off[i] = excl;
    cursor[i] = excl;
    if (i == NN - 1) off[NN] = excl + d;
  }
}

// ---------------- scatter edges into CSR + fused layer1 edge weights ----------------
__global__ void scatter_kernel(const int* __restrict__ ei, int* __restrict__ cursor,
                               const float* __restrict__ als, const float* __restrict__ ald,
                               int* __restrict__ esrc, int* __restrict__ edst,
                               float* __restrict__ ew) {
  int e = blockIdx.x * 256 + threadIdx.x;
  if (e >= NE) return;
  int s = ei[e];
  int d = ei[NE + e];
  int p = atomicAdd(&cursor[d], 1);
  esrc[p] = s;
  edst[p] = d;
  float4 as = *(const float4*)(als + s * 4);
  float4 ad = *(const float4*)(ald + d * 4);
  float4 w;
  w.x = __expf(lrelu(as.x + ad.x));
  w.y = __expf(lrelu(as.y + ad.y));
  w.z = __expf(lrelu(as.z + ad.z));
  w.w = __expf(lrelu(as.w + ad.w));
  *(float4*)(ew + p * 4) = w;
}

// ---------------- GAT layer1 aggregation: wave per node, 8-deep gather pipeline ------
__global__ __launch_bounds__(256) void agg1_kernel(const unsigned short* __restrict__ h1,
                                                   const float* __restrict__ als,
                                                   const float* __restrict__ ald,
                                                   const int* __restrict__ off,
                                                   const int* __restrict__ esrc,
                                                   const float* __restrict__ ew,
                                                   const float* __restrict__ b1,
                                                   unsigned short* __restrict__ out1) {
  int node = blockIdx.x * 4 + (threadIdx.x >> 6);
  int lane = threadIdx.x & 63;
  int hh = lane >> 4;
  int c0 = lane * 4;
  int beg = off[node], end = off[node + 1];
  float a0 = 0.f, a1 = 0.f, a2 = 0.f, a3 = 0.f, zz = 0.f;
  int k = beg;
  for (; k + 7 < end; k += 8) {
    int s[8];
    float w[8];
    ushort4 v[8];
#pragma unroll
    for (int j = 0; j < 8; j++) s[j] = esrc[k + j];
#pragma unroll
    for (int j = 0; j < 8; j++) {
      w[j] = ew[(k + j) * 4 + hh];
      v[j] = *(const ushort4*)(h1 + s[j] * HC + c0);
    }
#pragma unroll
    for (int j = 0; j < 8; j++) {
      a0 += w[j] * bf2f(v[j].x);
      a1 += w[j] * bf2f(v[j].y);
      a2 += w[j] * bf2f(v[j].z);
      a3 += w[j] * bf2f(v[j].w);
      zz += w[j];
    }
  }
  for (; k + 1 < end; k += 2) {
    int s0 = esrc[k], s1 = esrc[k + 1];
    float w0 = ew[k * 4 + hh], w1 = ew[(k + 1) * 4 + hh];
    ushort4 v0 = *(const ushort4*)(h1 + s0 * HC + c0);
    ushort4 v1 = *(const ushort4*)(h1 + s1 * HC + c0);
    a0 += w0 * bf2f(v0.x) + w1 * bf2f(v1.x);
    a1 += w0 * bf2f(v0.y) + w1 * bf2f(v1.y);
    a2 += w0 * bf2f(v0.z) + w1 * bf2f(v1.z);
    a3 += w0 * bf2f(v0.w) + w1 * bf2f(v1.w);
    zz += w0 + w1;
  }
  if (k < end) {
    int s0 = esrc[k];
    float w0 = ew[k * 4 + hh];
    ushort4 v0 = *(const ushort4*)(h1 + s0 * HC + c0);
    a0 += w0 * bf2f(v0.x);
    a1 += w0 * bf2f(v0.y);
    a2 += w0 * bf2f(v0.z);
    a3 += w0 * bf2f(v0.w);
    zz += w0;
  }
  // self-loop
  float sw = __expf(lrelu(als[node * NHEAD + hh] + ald[node * NHEAD + hh]));
  ushort4 vs = *(const ushort4*)(h1 + node * HC + c0);
  a0 += sw * bf2f(vs.x);
  a1 += sw * bf2f(vs.y);
  a2 += sw * bf2f(vs.z);
  a3 += sw * bf2f(vs.w);
  zz += sw;
  float inv = 1.f / zz;
  float4 bb = *(const float4*)(b1 + c0);
  ushort4 o;
  o.x = f2bf(a0 * inv + bb.x);
  o.y = f2bf(a1 * inv + bb.y);
  o.z = f2bf(a2 * inv + bb.z);
  o.w = f2bf(a3 * inv + bb.w);
  *(ushort4*)(out1 + node * HC + c0) = o;
}

// ---------------- BN stats over out1 ----------------
__global__ __launch_bounds__(256) void bnstats_kernel(const unsigned short* __restrict__ out1,
                                                      float* __restrict__ bnsum,
                                                      float* __restrict__ bnsumsq) {
  int t = threadIdx.x;
  float s = 0.f, s2 = 0.f;
  for (int r = blockIdx.x; r < NN; r += gridDim.x) {
    float v = bf2f(out1[r * HC + t]);
    s += v;
    s2 += v * v;
  }
  atomicAdd(&bnsum[t], s);
  atomicAdd(&bnsumsq[t], s2);
}

// ---------------- GEMM2 + fused als2/ald2: h2 = relu(bn(out1)) @ W2 ------------------
__global__ __launch_bounds__(256) void gemm2_kernel(const unsigned short* __restrict__ out1,
                                                    const unsigned short* __restrict__ W2p,
                                                    const float* __restrict__ bnsum,
                                                    const float* __restrict__ bnsumsq,
                                                    const float* __restrict__ gamma,
                                                    const float* __restrict__ beta,
                                                    const float* __restrict__ a_src2,
                                                    const float* __restrict__ a_dst2,
                                                    unsigned short* __restrict__ h2,
                                                    float* __restrict__ als2,
                                                    float* __restrict__ ald2) {
  __shared__ float scale_s[HC], shift_s[HC];
  __shared__ float sh_as[CDIM], sh_ad[CDIM];
  {
    int t = threadIdx.x;
    float mu = bnsum[t] / (float)NN;
    float var = bnsumsq[t] / (float)NN - mu * mu;
    float sc = gamma[t] * rsqrtf(var + 1e-5f);
    scale_s[t] = sc;
    shift_s[t] = beta[t] - mu * sc;
    if (t < CDIM) {
      sh_as[t] = a_src2[t];
      sh_ad[t] = a_dst2[t];
    }
  }
  __syncthreads();
  int wave = threadIdx.x >> 6, lane = threadIdx.x & 63;
  int tile = blockIdx.x * 4 + wave;
  if (tile >= NT1) return;
  int r0 = tile * 16, m = lane & 15, quad = lane >> 4;
  int row = r0 + m;
  short8 a[8];
#pragma unroll
  for (int kk = 0; kk < 8; kk++) {
    int kb = kk * 32 + quad * 8;
    short8 raw = *(const short8*)(out1 + row * HC + kb);
    alignas(16) unsigned short tmp[8];
#pragma unroll
    for (int j = 0; j < 8; j++) {
      tmp[j] = f2bf(relu(bf2f((unsigned short)raw[j]) * scale_s[kb + j] + shift_s[kb + j]));
    }
    a[kk] = *(const short8*)tmp;
  }
  float ps[4] = {0.f, 0.f, 0.f, 0.f};
  float pd[4] = {0.f, 0.f, 0.f, 0.f};
#pragma unroll
  for (int ng = 0; ng < 4; ng++) {
    f32x4 acc = {0.f, 0.f, 0.f, 0.f};
#pragma unroll
    for (int kk = 0; kk < 8; kk++) {
      short8 b = *(const short8*)(W2p + ((ng * 8 + kk) * 64 + lane) * 8);
      acc = __builtin_amdgcn_mfma_f32_16x16x32_bf16(a[kk], b, acc, 0, 0, 0);
    }
    int col = ng * 16 + m;
    float asv = sh_as[col], adv = sh_ad[col];
#pragma unroll
    for (int r = 0; r < 4; r++) {
      h2[(r0 + quad * 4 + r) * CDIM + col] = f2bf(acc[r]);
      ps[r] += acc[r] * asv;
      pd[r] += acc[r] * adv;
    }
  }
#pragma unroll
  for (int o = 1; o < 16; o <<= 1) {
#pragma unroll
    for (int r = 0; r < 4; r++) {
      ps[r] += __shfl_xor(ps[r], o, 64);
      pd[r] += __shfl_xor(pd[r], o, 64);
    }
  }
  if (m == 0) {
#pragma unroll
    for (int r = 0; r < 4; r++) {
      int rr = r0 + quad * 4 + r;
      als2[rr] = ps[r];
      ald2[rr] = pd[r];
    }
  }
}

// ---------------- edge weights layer2 ----------------
__global__ void ew2_kernel(const int* __restrict__ esrc, const int* __restrict__ edst,
                           const float* __restrict__ als2, const float* __restrict__ ald2,
                           float* __restrict__ ew2) {
  int k = blockIdx.x * 256 + threadIdx.x;
  if (k >= NE) return;
  ew2[k] = __expf(lrelu(als2[esrc[k]] + ald2[edst[k]]));
}

// ---------------- GAT layer2 aggregation + ReLU + pooling: wave/node, 8 edges/iter ---
__global__ __launch_bounds__(256) void agg2_kernel(const unsigned short* __restrict__ h2,
                                                   const float* __restrict__ als2,
                                                   const float* __restrict__ ald2,
                                                   const int* __restrict__ off,
                                                   const int* __restrict__ esrc,
                                                   const float* __restrict__ ew2,
                                                   const float* __restrict__ b2,
                                                   const int* __restrict__ batch,
                                                   float* __restrict__ pooled) {
  int node = blockIdx.x * 4 + (threadIdx.x >> 6);
  int lane = threadIdx.x & 63;
  int half = lane >> 5;
  int cp = (lane & 31) * 2;
  int beg = off[node], end = off[node + 1];
  float a0 = 0.f, a1 = 0.f, zz = 0.f;
  int k = beg;
  for (; k + 7 < end; k += 8) {
    int i0 = k + half, i1 = k + 2 + half, i2 = k + 4 + half, i3 = k + 6 + half;
    int s0 = esrc[i0], s1 = esrc[i1], s2 = esrc[i2], s3 = esrc[i3];
    float w0 = ew2[i0], w1 = ew2[i1], w2 = ew2[i2], w3 = ew2[i3];
    ushort2 v0 = *(const ushort2*)(h2 + s0 * CDIM + cp);
    ushort2 v1 = *(const ushort2*)(h2 + s1 * CDIM + cp);
    ushort2 v2 = *(const ushort2*)(h2 + s2 * CDIM + cp);
    ushort2 v3 = *(const ushort2*)(h2 + s3 * CDIM + cp);
    a0 += w0 * bf2f(v0.x) + w1 * bf2f(v1.x) + w2 * bf2f(v2.x) + w3 * bf2f(v3.x);
    a1 += w0 * bf2f(v0.y) + w1 * bf2f(v1.y) + w2 * bf2f(v2.y) + w3 * bf2f(v3.y);
    zz += w0 + w1 + w2 + w3;
  }
  for (; k + 3 < end; k += 4) {
    int i0 = k + half, i1 = k + 2 + half;
    int s0 = esrc[i0], s1 = esrc[i1];
    float w0 = ew2[i0], w1 = ew2[i1];
    ushort2 v0 = *(const ushort2*)(h2 + s0 * CDIM + cp);
    ushort2 v1 = *(const ushort2*)(h2 + s1 * CDIM + cp);
    a0 += w0 * bf2f(v0.x) + w1 * bf2f(v1.x);
    a1 += w0 * bf2f(v0.y) + w1 * bf2f(v1.y);
    zz += w0 + w1;
  }
  for (; k < end; k += 2) {
    int i0 = k + half;
    if (i0 < end) {
      int s0 = esrc[i0];
      float w0 = ew2[i0];
      ushort2 v0 = *(const ushort2*)(h2 + s0 * CDIM + cp);
      a0 += w0 * bf2f(v0.x);
      a1 += w0 * bf2f(v0.y);
      zz += w0;
    }
  }
  // combine the two halves (lanes L and L^32 cover the same channel pair)
  a0 += __shfl_xor(a0, 32, 64);
  a1 += __shfl_xor(a1, 32, 64);
  zz += __shfl_xor(zz, 32, 64);
  if (half == 0) {
    float sw = __expf(lrelu(als2[node] + ald2[node]));
    ushort2 vs = *(const ushort2*)(h2 + node * CDIM + cp);
    a0 += sw * bf2f(vs.x);
    a1 += sw * bf2f(vs.y);
    zz += sw;
    float inv = 1.f / zz;
    int g = batch[node];
    float v0 = relu(a0 * inv + b2[cp]);
    float v1 = relu(a1 * inv + b2[cp + 1]);
    atomicAdd(&pooled[g * CDIM + cp], v0);
    atomicAdd(&pooled[g * CDIM + cp + 1], v1);
  }
}

// ---------------- pooled mean + classifier (f32 output); counts via binary search ----
__global__ void cls_kernel(const float* __restrict__ pooled, const int* __restrict__ batch,
                           const float* __restrict__ cW1, const float* __restrict__ cb1,
                           const float* __restrict__ cW2, const float* __restrict__ cb2,
                           float* __restrict__ out) {
  __shared__ float p[64];
  __shared__ float z[32];
  int g = blockIdx.x, t = threadIdx.x;
  // batch is sorted: count nodes in graph g via two binary searches (wave-uniform)
  int lo = 0, hi = NN;
  while (lo < hi) { int mid = (lo + hi) >> 1; if (batch[mid] < g) lo = mid + 1; else hi = mid; }
  int start = lo;
  lo = 0; hi = NN;
  while (lo < hi) { int mid = (lo + hi) >> 1; if (batch[mid] <= g) lo = mid + 1; else hi = mid; }
  int c = lo - start;
  float cnt = (float)(c > 0 ? c : 1);
  p[t] = pooled[g * CDIM + t] / cnt;
  __syncthreads();
  if (t < 32) {
    float a = cb1[t];
    for (int k = 0; k < 64; k++) a += p[k] * cW1[k * 32 + t];
    z[t] = relu(a);
  }
  __syncthreads();
  if (t < NCLS) {
    float a = cb2[t];
    for (int k = 0; k < 32; k++) a += z[k] * cW2[k * NCLS + t];
    out[g * NCLS + t] = a;
  }
}

extern "C" void kernel_launch(void* const* d_in, const int* in_sizes, int n_in,
                              void* d_out, int out_size, void* d_ws, size_t ws_size,
                              hipStream_t stream) {
  const float* x = (const float*)d_in[0];
  const int* edge_index = (const int*)d_in[1];
  const int* batch = (const int*)d_in[2];
  const float* W1 = (const float*)d_in[3];
  const float* a_src1 = (const float*)d_in[4];
  const float* a_dst1 = (const float*)d_in[5];
  const float* b1 = (const float*)d_in[6];
  const float* gamma = (const float*)d_in[7];
  const float* beta = (const float*)d_in[8];
  const float* W2 = (const float*)d_in[9];
  const float* a_src2 = (const float*)d_in[10];
  const float* a_dst2 = (const float*)d_in[11];
  const float* b2 = (const float*)d_in[12];
  const float* cW1 = (const float*)d_in[13];
  const float* cb1 = (const float*)d_in[14];
  const float* cW2 = (const float*)d_in[15];
  const float* cb2 = (const float*)d_in[16];

  // ---- workspace layout ----
  // zero region (contiguous, zeroed every call): deg4 | bnsum | bnsumsq | pooled
  int* deg4 = (int*)d_ws;
  float* bnsum = (float*)(deg4 + 4 * NN);
  float* bnsumsq = bnsum + HC;
  float* pooled = bnsumsq + HC;
  const int ZWORDS = 4 * NN + HC + HC + NGRAPH * CDIM;
  char* p = (char*)(pooled + NGRAPH * CDIM);
  auto align256 = [&](char*& q) {
    size_t a = (size_t)(q - (char*)d_ws);
    a = (a + 255) & ~(size_t)255;
    q = (char*)d_ws + a;
  };
  align256(p);
  int* degsum = (int*)p;          p += (size_t)NN * 4;       align256(p);
  int* offs = (int*)p;            p += (size_t)(NN + 1) * 4; align256(p);
  int* cursor = (int*)p;          p += (size_t)NN * 4;       align256(p);
  int* esrc = (int*)p;            p += (size_t)NE * 4;       align256(p);
  int* edst = (int*)p;            p += (size_t)NE * 4;       align256(p);
  int* bsum = (int*)p;            p += 256 * 4;              align256(p);
  int* bscan = (int*)p;           p += 256 * 4;              align256(p);
  // h1 region; ew2 (NE*4 = 3.2MB) aliases its head: h1 dead after agg1, ew2 written later
  unsigned short* h1 = (unsigned short*)p;
  float* ew2 = (float*)p;         p += (size_t)NN * HC * 2;   align256(p);
  unsigned short* out1 = (unsigned short*)p; p += (size_t)NN * HC * 2;   align256(p);
  unsigned short* h2 = (unsigned short*)p;   p += (size_t)NN * CDIM * 2; align256(p);
  float* als1 = (float*)p;        p += (size_t)NN * NHEAD * 4; align256(p);
  float* ald1 = (float*)p;        p += (size_t)NN * NHEAD * 4; align256(p);
  float* als2v = (float*)p;       p += (size_t)NN * 4;         align256(p);
  float* ald2v = (float*)p;       p += (size_t)NN * 4;         align256(p);
  float* ew1 = (float*)p;         p += (size_t)NE * NHEAD * 4; align256(p);
  unsigned short* W1p = (unsigned short*)p; p += 32768 * 2;    align256(p);
  unsigned short* W2p = (unsigned short*)p; p += 16384 * 2;    align256(p);

  zero_kernel<<<(ZWORDS + 255) / 256, 256, 0, stream>>>((int*)d_ws, ZWORDS);
  repack_kernel<<<192, 256, 0, stream>>>(W1, W2, W1p, W2p);
  gemm1_kernel<<<(NT1 + 3) / 4, 256, 0, stream>>>(x, W1p, a_src1, a_dst1, h1, als1, ald1);
  hist_kernel<<<(NE + 255) / 256, 256, 0, stream>>>(edge_index, deg4);
  scan_a<<<NB, 256, 0, stream>>>(deg4, bsum, degsum);
  scan_b<<<1, 256, 0, stream>>>(bsum, bscan);
  scan_c<<<NB, 256, 0, stream>>>(degsum, bscan, offs, cursor);
  scatter_kernel<<<(NE + 255) / 256, 256, 0, stream>>>(edge_index, cursor, als1, ald1,
                                                       esrc, edst, ew1);
  agg1_kernel<<<NN / 4, 256, 0, stream>>>(h1, als1, ald1, offs, esrc, ew1, b1, out1);
  bnstats_kernel<<<1024, 256, 0, stream>>>(out1, bnsum, bnsumsq);
  gemm2_kernel<<<(NT1 + 3) / 4, 256, 0, stream>>>(out1, W2p, bnsum, bnsumsq, gamma, beta,
                                                  a_src2, a_dst2, h2, als2v, ald2v);
  ew2_kernel<<<(NE + 255) / 256, 256, 0, stream>>>(esrc, edst, als2v, ald2v, ew2);
  agg2_kernel<<<NN / 4, 256, 0, stream>>>(h2, als2v, ald2v, offs, esrc, ew2, b2, batch, pooled);
  cls_kernel<<<NGRAPH, 64, 0, stream>>>(pooled, batch, cW1, cb1, cW2, cb2, (float*)d_out);
}